// Round 4
// baseline (267.056 us; speedup 1.0000x reference)
//
#include <hip/hip_runtime.h>

// CausalAttention: B=4, S=2048, D=1024, single head over full D.
// R8 = R7 with STATIC 128 KB LDS (the dynamic-LDS + hipFuncSetAttribute
// path is a graph-capture/launch-validation hazard and the likely cause of
// R7's container failure). qkv + qk use the 256x256 8-phase core (T3+T4+T5):
// 512 threads (8 waves, 2M x 4N, per-wave 128x64 output), BK=64, 128 KB
// double-buffered static LDS. Per K-tile: 4 phases of {ds_read subtile |
// stage 4 gll16 | barrier | setprio(1) 16 MFMA setprio(0) | barrier}; one
// vmcnt(0) per K-tile placed after the last MFMA (loads get ~3 phases of
// slack). qk writes the packed-tri 128-row P layout (qt128 = 2qt + wm,
// uniform per wave). pv keeps the R6 balanced 64x128 2-phase core.

typedef __attribute__((ext_vector_type(8))) _Float16 f16x8;
typedef __attribute__((ext_vector_type(4))) _Float16 f16x4;
typedef __attribute__((ext_vector_type(4))) float f32x4;

#define NB   4
#define SEQ  2048
#define DIM  1024
#define SCL  0.03125f   // 1/sqrt(1024)
#define PBATCH (136 * 16384)   // packed P elems per batch (tri(16) tiles)

__device__ __forceinline__ void gll16(const _Float16* g, _Float16* l) {
  __builtin_amdgcn_global_load_lds(
      (__attribute__((address_space(1))) void*)(g),
      (__attribute__((address_space(3))) void*)(l), 16, 0, 0);
}

// ---------------- 256x256 8-phase core (qkv, qk) ----------------
// As/Bs [2][256][64] fp16 (64 KB each, static LDS). Row = 128 B, swizzle
// chunk' = chunk ^ (row&7) over the 8 16B-chunks/row (same scheme as the
// verified 2-phase core; 0 bank conflicts measured).
// Staging: 4 gll16 lines per operand per K-tile; thread t covers
//   row = l*64 + wv*8 + (ln>>3), slot chunk = ln&7, src chunk = slot^(ln>>3).
// 8 waves: wm = wv&1 (M half), wn = wv>>1 (N quarter); per-wave 128x64 out,
// acc[8][4], 64 MFMA per K-tile = 4 phases x 16.
template<int NT>
__device__ __forceinline__ void gemm256(
    const _Float16* __restrict__ A, int lda,
    const _Float16* __restrict__ Bm, int ldb,
    _Float16* __restrict__ As, _Float16* __restrict__ Bs,
    f32x4 acc[8][4])
{
  const int t    = threadIdx.x;
  const int wv   = t >> 6;
  const int ln   = t & 63;
  const int lr   = ln & 15;
  const int lq   = ln >> 4;
  const int rsub = ln >> 3;
  const int colb = (((ln & 7) ^ rsub) * 8);

  const _Float16* ga[4]; const _Float16* gb[4];
  int dA[4];
#pragma unroll
  for (int l = 0; l < 4; ++l) {
    const int row = l * 64 + wv * 8 + rsub;
    ga[l] = A  + row * lda + colb;
    gb[l] = Bm + row * ldb + colb;
    dA[l] = (l * 64 + wv * 8) * 64;   // wave-uniform LDS elem offset
  }

  const int wm   = wv & 1;
  const int wn   = wv >> 1;
  const int swzr = lr & 7;
  const int rowA = (wm * 128 + lr) * 64;
  const int rowB = (wn * 64  + lr) * 64;
  const int ck0  = ((lq)     ^ swzr) * 8;
  const int ck1  = ((4 + lq) ^ swzr) * 8;

  // prologue: stage K-tile 0 into buffer 0
#pragma unroll
  for (int l = 0; l < 4; ++l) gll16(ga[l], As + dA[l]);
#pragma unroll
  for (int l = 0; l < 4; ++l) gll16(gb[l], Bs + dA[l]);
  asm volatile("s_waitcnt vmcnt(0)" ::: "memory");
  __builtin_amdgcn_s_barrier();

  for (int tt = 0; tt < NT; ++tt) {
    const int cb = (tt & 1) * 16384;
    const int nb = cb ^ 16384;
    const bool st = (tt + 1 < NT);
    const int k1 = (tt + 1) * 64;
    f16x8 af[4], bf[4];

    // ---- phase 0: reads grp0(ks0) + B(ks0); stage A of tile t+1
#pragma unroll
    for (int mi = 0; mi < 4; ++mi) af[mi] = *(const f16x8*)(As + cb + rowA + mi * 1024 + ck0);
#pragma unroll
    for (int ni = 0; ni < 4; ++ni) bf[ni] = *(const f16x8*)(Bs + cb + rowB + ni * 1024 + ck0);
    if (st) {
#pragma unroll
      for (int l = 0; l < 4; ++l) gll16(ga[l] + k1, As + nb + dA[l]);
    }
    __builtin_amdgcn_s_barrier();
    __builtin_amdgcn_s_setprio(1);
#pragma unroll
    for (int mi = 0; mi < 4; ++mi)
#pragma unroll
      for (int ni = 0; ni < 4; ++ni)
        acc[mi][ni] = __builtin_amdgcn_mfma_f32_16x16x32_f16(af[mi], bf[ni], acc[mi][ni], 0, 0, 0);
    __builtin_amdgcn_s_setprio(0);
    __builtin_amdgcn_s_barrier();

    // ---- phase 1: reads grp1(ks0); stage B of tile t+1
#pragma unroll
    for (int mi = 0; mi < 4; ++mi) af[mi] = *(const f16x8*)(As + cb + rowA + (4 + mi) * 1024 + ck0);
    if (st) {
#pragma unroll
      for (int l = 0; l < 4; ++l) gll16(gb[l] + k1, Bs + nb + dA[l]);
    }
    __builtin_amdgcn_s_barrier();
    __builtin_amdgcn_s_setprio(1);
#pragma unroll
    for (int mi = 0; mi < 4; ++mi)
#pragma unroll
      for (int ni = 0; ni < 4; ++ni)
        acc[4 + mi][ni] = __builtin_amdgcn_mfma_f32_16x16x32_f16(af[mi], bf[ni], acc[4 + mi][ni], 0, 0, 0);
    __builtin_amdgcn_s_setprio(0);
    __builtin_amdgcn_s_barrier();

    // ---- phase 2: reads grp0(ks1) + B(ks1)
#pragma unroll
    for (int mi = 0; mi < 4; ++mi) af[mi] = *(const f16x8*)(As + cb + rowA + mi * 1024 + ck1);
#pragma unroll
    for (int ni = 0; ni < 4; ++ni) bf[ni] = *(const f16x8*)(Bs + cb + rowB + ni * 1024 + ck1);
    __builtin_amdgcn_s_barrier();
    __builtin_amdgcn_s_setprio(1);
#pragma unroll
    for (int mi = 0; mi < 4; ++mi)
#pragma unroll
      for (int ni = 0; ni < 4; ++ni)
        acc[mi][ni] = __builtin_amdgcn_mfma_f32_16x16x32_f16(af[mi], bf[ni], acc[mi][ni], 0, 0, 0);
    __builtin_amdgcn_s_setprio(0);
    __builtin_amdgcn_s_barrier();

    // ---- phase 3: reads grp1(ks1); tile-boundary vmcnt after MFMA
#pragma unroll
    for (int mi = 0; mi < 4; ++mi) af[mi] = *(const f16x8*)(As + cb + rowA + (4 + mi) * 1024 + ck1);
    __builtin_amdgcn_s_barrier();
    __builtin_amdgcn_s_setprio(1);
#pragma unroll
    for (int mi = 0; mi < 4; ++mi)
#pragma unroll
      for (int ni = 0; ni < 4; ++ni)
        acc[4 + mi][ni] = __builtin_amdgcn_mfma_f32_16x16x32_f16(af[mi], bf[ni], acc[4 + mi][ni], 0, 0, 0);
    __builtin_amdgcn_s_setprio(0);
    asm volatile("s_waitcnt vmcnt(0)" ::: "memory");  // t+1's 8 loads landed
    __builtin_amdgcn_s_barrier();
  }
}

// ---------------- BK=64 double-buffered 2-phase core (pv) ----------------
template<int AR, int BR>
__device__ __forceinline__ void gemm_core64_db(
    const _Float16* __restrict__ A, int lda,
    const _Float16* __restrict__ Bm, int ldb,
    int K, _Float16* As, _Float16* Bs, f32x4 acc[AR/32][BR/32])
{
  constexpr int LA = AR / 32;
  constexpr int LB = BR / 32;
  constexpr int MI = AR / 32;
  constexpr int NI = BR / 32;
  constexpr int AHALF = AR * 64;
  constexpr int BHALF = BR * 64;

  const int t    = threadIdx.x;
  const int wv   = t >> 6;
  const int ln   = t & 63;
  const int lr   = ln & 15;
  const int lq   = ln >> 4;
  const int rsub = ln >> 3;
  const int colb = (((ln & 7) ^ rsub) * 8);

  const _Float16* ga[LA]; _Float16* dA[LA];
  const _Float16* gb[LB]; _Float16* dB[LB];
#pragma unroll
  for (int l = 0; l < LA; ++l) {
    const int row = (4 * l + wv) * 8 + rsub;
    ga[l] = A + row * lda + colb;
    dA[l] = As + (4 * l + wv) * 512;
  }
#pragma unroll
  for (int l = 0; l < LB; ++l) {
    const int row = (4 * l + wv) * 8 + rsub;
    gb[l] = Bm + row * ldb + colb;
    dB[l] = Bs + (4 * l + wv) * 512;
  }

  const int swzr = lr & 7;
  const int ra = (((wv & 1) * (AR / 2)) + lr) * 64;
  const int rb = (((wv >> 1) * (BR / 2)) + lr) * 64;
  const int c0 = ((0 * 4 + lq) ^ swzr) * 8;
  const int c1 = ((1 * 4 + lq) ^ swzr) * 8;

  auto compute = [&](int half) {
    const _Float16* pa = As + half * AHALF + ra;
    const _Float16* pb = Bs + half * BHALF + rb;
    f16x8 af[MI][2], bf[NI][2];
#pragma unroll
    for (int mi = 0; mi < MI; ++mi) {
      af[mi][0] = *(const f16x8*)(pa + mi * 1024 + c0);
      af[mi][1] = *(const f16x8*)(pa + mi * 1024 + c1);
    }
#pragma unroll
    for (int ni = 0; ni < NI; ++ni) {
      bf[ni][0] = *(const f16x8*)(pb + ni * 1024 + c0);
      bf[ni][1] = *(const f16x8*)(pb + ni * 1024 + c1);
    }
#pragma unroll
    for (int ks = 0; ks < 2; ++ks)
#pragma unroll
      for (int mi = 0; mi < MI; ++mi)
#pragma unroll
        for (int ni = 0; ni < NI; ++ni)
          acc[mi][ni] = __builtin_amdgcn_mfma_f32_16x16x32_f16(
              af[mi][ks], bf[ni][ks], acc[mi][ni], 0, 0, 0);
  };

#pragma unroll
  for (int l = 0; l < LA; ++l) gll16(ga[l], dA[l]);
#pragma unroll
  for (int l = 0; l < LB; ++l) gll16(gb[l], dB[l]);

  int cur = 0;
  for (int k0 = 64; k0 < K; k0 += 64) {
    const int nxt = cur ^ 1;
#pragma unroll
    for (int l = 0; l < LA; ++l) gll16(ga[l] + k0, dA[l] + nxt * AHALF);
#pragma unroll
    for (int l = 0; l < LB; ++l) gll16(gb[l] + k0, dB[l] + nxt * BHALF);
    if constexpr (LA + LB == 8)
      asm volatile("s_waitcnt vmcnt(8)" ::: "memory");
    else
      asm volatile("s_waitcnt vmcnt(6)" ::: "memory");
    __builtin_amdgcn_s_barrier();
    compute(cur);
    __builtin_amdgcn_s_barrier();
    cur = nxt;
  }
  asm volatile("s_waitcnt vmcnt(0)" ::: "memory");
  __builtin_amdgcn_s_barrier();
  compute(cur);
}

// one kernel converts x, Wq, Wk, Wv (blockIdx.y selects segment)
__global__ __launch_bounds__(256) void cvt_all(
    const float* __restrict__ x, const float* __restrict__ Wq,
    const float* __restrict__ Wk, const float* __restrict__ Wv,
    _Float16* __restrict__ xb, _Float16* __restrict__ Wb)
{
  const float* src; _Float16* dst; int n;
  const int M1 = 1024 * 1024;
  switch (blockIdx.y) {
    case 0: src = x;  dst = xb;          n = NB * SEQ * DIM; break;
    case 1: src = Wq; dst = Wb;          n = M1; break;
    case 2: src = Wk; dst = Wb + M1;     n = M1; break;
    default: src = Wv; dst = Wb + 2*M1;  n = M1; break;
  }
  int i = (blockIdx.x * 256 + threadIdx.x) * 4;
  const int stride = gridDim.x * 256 * 4;
  for (; i < n; i += stride) {
    const float4 v = *(const float4*)(src + i);
    f16x4 o;
    o.x = (_Float16)v.x; o.y = (_Float16)v.y; o.z = (_Float16)v.z; o.w = (_Float16)v.w;
    *(f16x4*)(dst + i) = o;
  }
}

// 256x256 tiles over [M=8192, Ncat=3072]; z = ncat>>10 selects Q/K/V.
__global__ __launch_bounds__(512, 2) void qkv_gemm(
    const _Float16* __restrict__ xb, const _Float16* __restrict__ Wb,
    const float* __restrict__ bq, const float* __restrict__ bk,
    const float* __restrict__ bv,
    _Float16* __restrict__ Qb, _Float16* __restrict__ Kb, _Float16* __restrict__ Vt)
{
  __shared__ _Float16 As[32768];   // 2 x 256 x 64
  __shared__ _Float16 Bs[32768];
  const int m0 = blockIdx.x * 256;
  const int ng = blockIdx.y * 256;
  const int z  = ng >> 10;
  const int n0 = ng & 1023;

  f32x4 acc[8][4];
#pragma unroll
  for (int mi = 0; mi < 8; ++mi)
#pragma unroll
    for (int ni = 0; ni < 4; ++ni) acc[mi][ni] = {0.f, 0.f, 0.f, 0.f};

  gemm256<16>(xb + (size_t)m0 * DIM, DIM,
              Wb + (size_t)z * DIM * DIM + (size_t)n0 * DIM, DIM,
              As, Bs, acc);

  const int t = threadIdx.x, wv = t >> 6, ln = t & 63, lr = ln & 15, lq = ln >> 4;
  const int wm = wv & 1, wn = wv >> 1;
  const float* bias = (z == 0) ? bq : (z == 1) ? bk : bv;
  if (z < 2) {
    _Float16* O = (z == 0) ? Qb : Kb;
#pragma unroll
    for (int ni = 0; ni < 4; ++ni) {
      const int col = n0 + wn * 64 + ni * 16 + lr;
      const float bb = bias[col];
#pragma unroll
      for (int mi = 0; mi < 8; ++mi) {
        const int r0 = m0 + wm * 128 + mi * 16 + lq * 4;
#pragma unroll
        for (int r = 0; r < 4; ++r)
          O[(size_t)(r0 + r) * DIM + col] = (_Float16)(acc[mi][ni][r] + bb);
      }
    }
  } else {
#pragma unroll
    for (int ni = 0; ni < 4; ++ni) {
      const int col = n0 + wn * 64 + ni * 16 + lr;
      const float bb = bias[col];
#pragma unroll
      for (int mi = 0; mi < 8; ++mi) {
        const int r0 = m0 + wm * 128 + mi * 16 + lq * 4;
        const int b = r0 >> 11, s = r0 & 2047;
        f16x4 pk;
#pragma unroll
        for (int r = 0; r < 4; ++r) pk[r] = (_Float16)(acc[mi][ni][r] + bb);
        *(f16x4*)(Vt + (size_t)b * DIM * SEQ + (size_t)col * SEQ + s) = pk;
      }
    }
  }
}

// Fused QK^T + exp + row-sum on 256x256 tri tiles (qt,kt in 0..7, kt<=qt).
// Writes the packed-tri 128-row P layout pv consumes: per wave qt128=2qt+wm.
__global__ __launch_bounds__(512, 2) void qk_gemm(
    const _Float16* __restrict__ Qb, const _Float16* __restrict__ Kb,
    _Float16* __restrict__ Pm, float* __restrict__ lsum)
{
  __shared__ _Float16 As[32768];   // 2 x 256 x 64
  __shared__ _Float16 Bs[32768];
  const int idx = blockIdx.x;
  int qt = 0;
  while ((qt + 1) * (qt + 2) / 2 <= idx) ++qt;
  const int kt = idx - qt * (qt + 1) / 2;
  const int q0 = qt * 256, k0 = kt * 256, b = blockIdx.y;

  f32x4 acc[8][4];
#pragma unroll
  for (int mi = 0; mi < 8; ++mi)
#pragma unroll
    for (int ni = 0; ni < 4; ++ni) acc[mi][ni] = {0.f, 0.f, 0.f, 0.f};

  const _Float16* Qp = Qb + (size_t)b * SEQ * DIM + (size_t)q0 * DIM;
  const _Float16* Kp = Kb + (size_t)b * SEQ * DIM + (size_t)k0 * DIM;
  gemm256<16>(Qp, DIM, Kp, DIM, As, Bs, acc);

  const int t = threadIdx.x, wv = t >> 6, ln = t & 63, lr = ln & 15, lq = ln >> 4;
  const int wm = wv & 1, wn = wv >> 1;
  const int qt128 = 2 * qt + wm;                   // uniform per wave
  const int ldp = (qt128 + 1) * 128;
  _Float16* scr = Pm + (size_t)b * PBATCH + (size_t)(qt128 * (qt128 + 1) / 2) * 16384;
  float* lrow = lsum + b * SEQ;

  float es[8][4];
#pragma unroll
  for (int mi = 0; mi < 8; ++mi)
#pragma unroll
    for (int r = 0; r < 4; ++r) es[mi][r] = 0.f;

#pragma unroll
  for (int ni = 0; ni < 4; ++ni) {
    const int col = k0 + wn * 64 + ni * 16 + lr;
    const bool cin = col < ldp;
#pragma unroll
    for (int mi = 0; mi < 8; ++mi) {
#pragma unroll
      for (int r = 0; r < 4; ++r) {
        const int rin = mi * 16 + lq * 4 + r;      // 0..127 within row group
        const int row = q0 + wm * 128 + rin;
        const float s = acc[mi][ni][r] * SCL;
        const float e = (col <= row) ? __expf(fminf(s, 10.f)) : 0.f;
        if (cin) scr[(size_t)rin * ldp + col] = (_Float16)e;
        es[mi][r] += e;
      }
    }
  }
#pragma unroll
  for (int mi = 0; mi < 8; ++mi)
#pragma unroll
    for (int r = 0; r < 4; ++r) {
      float v = es[mi][r];
#pragma unroll
      for (int off = 1; off < 16; off <<= 1) v += __shfl_xor(v, off, 64);
      if (lr == 0) {
        const int row = q0 + wm * 128 + mi * 16 + lq * 4 + r;
        atomicAdd(&lrow[row], v);
      }
    }
}

// out[b][q][d] = (sum_k e[q][k] * Vt[b][d][k]) / l[b][q].
// q split into 32 subtiles of 64 rows, paired j & 31-j -> 17 K-tiles/block.
__global__ __launch_bounds__(256, 2) void pv_gemm(
    const _Float16* __restrict__ Pm, const _Float16* __restrict__ Vt,
    const float* __restrict__ lsum, float* __restrict__ out)
{
  __shared__ _Float16 As[8192];     // 2 x 64 x 64
  __shared__ _Float16 Bs[16384];    // 2 x 128 x 64
  const int p  = blockIdx.x;        // 0..15
  const int d0 = blockIdx.y * 128;
  const int b  = blockIdx.z;

  const int t = threadIdx.x, wv = t >> 6, ln = t & 63, lr = ln & 15, lq = ln >> 4;
  const int wm = wv & 1, wn = wv >> 1;
  float* O = out + (size_t)b * SEQ * DIM;
  const float* lrow = lsum + b * SEQ;
  const _Float16* Vp = Vt + (size_t)b * DIM * SEQ + (size_t)d0 * SEQ;

  const int js[2] = { 31 - p, p };  // big subtile first
#pragma unroll
  for (int u = 0; u < 2; ++u) {
    const int j  = js[u];
    const int qt = j >> 1;
    const int q0 = qt * 128 + (j & 1) * 64;
    const int K  = (qt + 1) * 128;
    if (u) __syncthreads();

    f32x4 acc[2][4];
#pragma unroll
    for (int mi = 0; mi < 2; ++mi)
#pragma unroll
      for (int ni = 0; ni < 4; ++ni) acc[mi][ni] = {0.f, 0.f, 0.f, 0.f};

    const _Float16* Pp = Pm + (size_t)b * PBATCH
        + (size_t)(qt * (qt + 1) / 2) * 16384 + (size_t)(j & 1) * 64 * K;
    gemm_core64_db<64,128>(Pp, K, Vp, SEQ, K, As, Bs, acc);

#pragma unroll
    for (int mi = 0; mi < 2; ++mi) {
      const int r0 = q0 + wm * 32 + mi * 16 + lq * 4;
      const float4 lv = *(const float4*)(lrow + r0);
      const float inv[4] = {1.f / lv.x, 1.f / lv.y, 1.f / lv.z, 1.f / lv.w};
#pragma unroll
      for (int ni = 0; ni < 4; ++ni) {
        const int col = d0 + wn * 64 + ni * 16 + lr;
#pragma unroll
        for (int r = 0; r < 4; ++r)
          O[(size_t)(r0 + r) * DIM + col] = acc[mi][ni][r] * inv[r];
      }
    }
  }
}

extern "C" void kernel_launch(void* const* d_in, const int* in_sizes, int n_in,
                              void* d_out, int out_size, void* d_ws, size_t ws_size,
                              hipStream_t stream) {
  const float* x  = (const float*)d_in[0];
  const float* Wq = (const float*)d_in[1];
  const float* bq = (const float*)d_in[2];
  const float* Wk = (const float*)d_in[3];
  const float* bk = (const float*)d_in[4];
  const float* Wv = (const float*)d_in[5];
  const float* bv = (const float*)d_in[6];
  float* out = (float*)d_out;

  _Float16* w16 = (_Float16*)d_ws;
  const size_t M1 = (size_t)1024 * 1024;
  _Float16* Qb = w16;                 //  0M .. 8M el (16 MB)
  _Float16* Kb = w16 + 8 * M1;        //  8M .. 16M
  _Float16* Vt = w16 + 16 * M1;       // 16M .. 24M  (V transposed [b][d][s])
  _Float16* xb = w16 + 24 * M1;       // 24M .. 32M  (dead after qkv_gemm)
  _Float16* Wb = w16 + 32 * M1;       // 32M .. 35M  (dead after qkv_gemm)
  _Float16* Pm = w16 + 24 * M1;       // packed tri P (17.8 MB), aliases xb
  float*    lsum = (float*)(w16 + 34 * M1);  // 32 KB row sums

  hipMemsetAsync(lsum, 0, NB * SEQ * sizeof(float), stream);
  cvt_all<<<dim3(512, 4), 256, 0, stream>>>(x, Wq, Wk, Wv, xb, Wb);
  qkv_gemm<<<dim3(32, 12), 512, 0, stream>>>(xb, Wb, bq, bk, bv, Qb, Kb, Vt);
  qk_gemm<<<dim3(36, NB), 512, 0, stream>>>(Qb, Kb, Pm, lsum);
  pv_gemm<<<dim3(16, 8, NB), 256, 0, stream>>>(Pm, Vt, lsum, out);
}

// Round 5
// 258.248 us; speedup vs baseline: 1.0341x; 1.0341x over previous
//
#include <hip/hip_runtime.h>

// CausalAttention: B=4, S=2048, D=1024, single head over full D.
// R9: fix R8's broken pipeline. R8 drained vmcnt(0) every K-tile (depth-1
// prefetch -> boundary wait must be a full drain) — the documented
// anti-pattern (m218: counted-vs-drain0 = +38-73%). New 256x256 core:
// BK=32, THREE LDS buffers (96 KB), stage tile t+2 while computing tile t,
// boundary wait = vmcnt(4) (t+1 landed, t+2 in flight) — never 0 in the
// main loop — and ONE barrier per K-tile. 32 MFMA : 4 gll16 : 1 barrier.
// setprio(1) around each 16-MFMA cluster. qkv + qk use this core; pv keeps
// the R6 balanced 2-phase core; cvt unchanged.

typedef __attribute__((ext_vector_type(8))) _Float16 f16x8;
typedef __attribute__((ext_vector_type(4))) _Float16 f16x4;
typedef __attribute__((ext_vector_type(4))) float f32x4;

#define NB   4
#define SEQ  2048
#define DIM  1024
#define SCL  0.03125f   // 1/sqrt(1024)
#define PBATCH (136 * 16384)   // packed P elems per batch (tri(16) tiles)

__device__ __forceinline__ void gll16(const _Float16* g, _Float16* l) {
  __builtin_amdgcn_global_load_lds(
      (__attribute__((address_space(1))) void*)(g),
      (__attribute__((address_space(3))) void*)(l), 16, 0, 0);
}

// ---------------- 256x256 BK=32 triple-buffered core (qkv, qk) ----------------
// As/Bs: 3 buffers x [256][32] fp16 (16 KB each; 96 KB total static LDS).
// Row = 64 B; swizzle chunk' = chunk ^ ((row>>1)&3) over the 4 16B-chunks/row
// -> 2-way bank aliasing (free). Staging: 2 gll16 per operand per K-tile;
// thread t covers row = l*128 + (t>>2), slot chunk = t&3,
// src chunk = (t&3) ^ (((t>>2)>>1)&3); LDS dest linear = t*16 B.
// 8 waves (2M x 4N): per-wave output 128x64, acc[8][4].
// Pipeline per K-tile t: {ds_read 8 frags | stage tile t+2 (4 gll) |
// setprio 16 MFMA grp0 | ds_read 4 frags | setprio 16 MFMA grp1 |
// vmcnt(4) | barrier}. Prologue stages tiles 0,1; epilogue drains naturally.
template<int NT>
__device__ __forceinline__ void gemm256(
    const _Float16* __restrict__ A, int lda,
    const _Float16* __restrict__ Bm, int ldb,
    _Float16* __restrict__ As, _Float16* __restrict__ Bs,
    f32x4 acc[8][4])
{
  const int t    = threadIdx.x;
  const int wv   = t >> 6;
  const int ln   = t & 63;
  const int lr   = ln & 15;
  const int lq   = ln >> 4;

  // staging addresses
  const int srow   = t >> 2;                       // 0..127 (load l adds 128)
  const int schunk = (t & 3) ^ ((srow >> 1) & 3);  // swizzled source chunk
  const _Float16* ga0 = A  + (size_t)srow * lda + schunk * 8;
  const _Float16* ga1 = ga0 + (size_t)128 * lda;
  const _Float16* gb0 = Bm + (size_t)srow * ldb + schunk * 8;
  const _Float16* gb1 = gb0 + (size_t)128 * ldb;
  const int dst0 = wv * 512;                       // elems; +4096 for l=1

  // fragment read bases (elems)
  const int wm = wv & 1;
  const int wn = wv >> 1;
  const int ck = (lq ^ ((lr >> 1) & 3)) * 8;
  const int ra = (wm * 128 + lr) * 32 + ck;
  const int rb = (wn * 64  + lr) * 32 + ck;

  // prologue: stage tiles 0 and 1 into buffers 0 and 1
  gll16(ga0, As + dst0);          gll16(ga1, As + dst0 + 4096);
  gll16(gb0, Bs + dst0);          gll16(gb1, Bs + dst0 + 4096);
  gll16(ga0 + 32, As + 8192 + dst0); gll16(ga1 + 32, As + 8192 + dst0 + 4096);
  gll16(gb0 + 32, Bs + 8192 + dst0); gll16(gb1 + 32, Bs + 8192 + dst0 + 4096);
  asm volatile("s_waitcnt vmcnt(4)" ::: "memory");   // tile 0 landed
  __builtin_amdgcn_s_barrier();

  int c0 = 0, c1 = 8192, c2 = 16384;   // compute buf, next buf, stage buf
  for (int tt = 0; tt < NT; ++tt) {
    f16x8 af[4], bf[4], ag[4];
    // phase A fragment reads (grp0 A rows + all B rows)
#pragma unroll
    for (int mi = 0; mi < 4; ++mi) af[mi] = *(const f16x8*)(As + c0 + ra + mi * 512);
#pragma unroll
    for (int ni = 0; ni < 4; ++ni) bf[ni] = *(const f16x8*)(Bs + c0 + rb + ni * 512);
    // stage tile t+2 into c2 (buffer last read at tile t-1; barrier passed)
    if (tt + 2 < NT) {
      const int k2 = (tt + 2) * 32;
      gll16(ga0 + k2, As + c2 + dst0);  gll16(ga1 + k2, As + c2 + dst0 + 4096);
      gll16(gb0 + k2, Bs + c2 + dst0);  gll16(gb1 + k2, Bs + c2 + dst0 + 4096);
    }
    __builtin_amdgcn_s_setprio(1);
#pragma unroll
    for (int mi = 0; mi < 4; ++mi)
#pragma unroll
      for (int ni = 0; ni < 4; ++ni)
        acc[mi][ni] = __builtin_amdgcn_mfma_f32_16x16x32_f16(af[mi], bf[ni], acc[mi][ni], 0, 0, 0);
    __builtin_amdgcn_s_setprio(0);
    // phase B fragment reads (grp1 A rows)
#pragma unroll
    for (int mi = 0; mi < 4; ++mi) ag[mi] = *(const f16x8*)(As + c0 + ra + (4 + mi) * 512);
    __builtin_amdgcn_s_setprio(1);
#pragma unroll
    for (int mi = 0; mi < 4; ++mi)
#pragma unroll
      for (int ni = 0; ni < 4; ++ni)
        acc[4 + mi][ni] = __builtin_amdgcn_mfma_f32_16x16x32_f16(ag[mi], bf[ni], acc[4 + mi][ni], 0, 0, 0);
    __builtin_amdgcn_s_setprio(0);
    // boundary: wait tile t+1 landed (t+2's 4 loads stay in flight)
    if (tt + 2 < NT)
      asm volatile("s_waitcnt vmcnt(4)" ::: "memory");
    else if (tt + 1 < NT)
      asm volatile("s_waitcnt vmcnt(0)" ::: "memory");
    if (tt + 1 < NT) __builtin_amdgcn_s_barrier();
    const int tmp = c0; c0 = c1; c1 = c2; c2 = tmp;
  }
}

// ---------------- BK=64 double-buffered 2-phase core (pv) ----------------
template<int AR, int BR>
__device__ __forceinline__ void gemm_core64_db(
    const _Float16* __restrict__ A, int lda,
    const _Float16* __restrict__ Bm, int ldb,
    int K, _Float16* As, _Float16* Bs, f32x4 acc[AR/32][BR/32])
{
  constexpr int LA = AR / 32;
  constexpr int LB = BR / 32;
  constexpr int MI = AR / 32;
  constexpr int NI = BR / 32;
  constexpr int AHALF = AR * 64;
  constexpr int BHALF = BR * 64;

  const int t    = threadIdx.x;
  const int wv   = t >> 6;
  const int ln   = t & 63;
  const int lr   = ln & 15;
  const int lq   = ln >> 4;
  const int rsub = ln >> 3;
  const int colb = (((ln & 7) ^ rsub) * 8);

  const _Float16* ga[LA]; _Float16* dA[LA];
  const _Float16* gb[LB]; _Float16* dB[LB];
#pragma unroll
  for (int l = 0; l < LA; ++l) {
    const int row = (4 * l + wv) * 8 + rsub;
    ga[l] = A + row * lda + colb;
    dA[l] = As + (4 * l + wv) * 512;
  }
#pragma unroll
  for (int l = 0; l < LB; ++l) {
    const int row = (4 * l + wv) * 8 + rsub;
    gb[l] = Bm + row * ldb + colb;
    dB[l] = Bs + (4 * l + wv) * 512;
  }

  const int swzr = lr & 7;
  const int ra = (((wv & 1) * (AR / 2)) + lr) * 64;
  const int rb = (((wv >> 1) * (BR / 2)) + lr) * 64;
  const int c0 = ((0 * 4 + lq) ^ swzr) * 8;
  const int c1 = ((1 * 4 + lq) ^ swzr) * 8;

  auto compute = [&](int half) {
    const _Float16* pa = As + half * AHALF + ra;
    const _Float16* pb = Bs + half * BHALF + rb;
    f16x8 af[MI][2], bf[NI][2];
#pragma unroll
    for (int mi = 0; mi < MI; ++mi) {
      af[mi][0] = *(const f16x8*)(pa + mi * 1024 + c0);
      af[mi][1] = *(const f16x8*)(pa + mi * 1024 + c1);
    }
#pragma unroll
    for (int ni = 0; ni < NI; ++ni) {
      bf[ni][0] = *(const f16x8*)(pb + ni * 1024 + c0);
      bf[ni][1] = *(const f16x8*)(pb + ni * 1024 + c1);
    }
#pragma unroll
    for (int ks = 0; ks < 2; ++ks)
#pragma unroll
      for (int mi = 0; mi < MI; ++mi)
#pragma unroll
        for (int ni = 0; ni < NI; ++ni)
          acc[mi][ni] = __builtin_amdgcn_mfma_f32_16x16x32_f16(
              af[mi][ks], bf[ni][ks], acc[mi][ni], 0, 0, 0);
  };

#pragma unroll
  for (int l = 0; l < LA; ++l) gll16(ga[l], dA[l]);
#pragma unroll
  for (int l = 0; l < LB; ++l) gll16(gb[l], dB[l]);

  int cur = 0;
  for (int k0 = 64; k0 < K; k0 += 64) {
    const int nxt = cur ^ 1;
#pragma unroll
    for (int l = 0; l < LA; ++l) gll16(ga[l] + k0, dA[l] + nxt * AHALF);
#pragma unroll
    for (int l = 0; l < LB; ++l) gll16(gb[l] + k0, dB[l] + nxt * BHALF);
    if constexpr (LA + LB == 8)
      asm volatile("s_waitcnt vmcnt(8)" ::: "memory");
    else
      asm volatile("s_waitcnt vmcnt(6)" ::: "memory");
    __builtin_amdgcn_s_barrier();
    compute(cur);
    __builtin_amdgcn_s_barrier();
    cur = nxt;
  }
  asm volatile("s_waitcnt vmcnt(0)" ::: "memory");
  __builtin_amdgcn_s_barrier();
  compute(cur);
}

// one kernel converts x, Wq, Wk, Wv (blockIdx.y selects segment)
__global__ __launch_bounds__(256) void cvt_all(
    const float* __restrict__ x, const float* __restrict__ Wq,
    const float* __restrict__ Wk, const float* __restrict__ Wv,
    _Float16* __restrict__ xb, _Float16* __restrict__ Wb)
{
  const float* src; _Float16* dst; int n;
  const int M1 = 1024 * 1024;
  switch (blockIdx.y) {
    case 0: src = x;  dst = xb;          n = NB * SEQ * DIM; break;
    case 1: src = Wq; dst = Wb;          n = M1; break;
    case 2: src = Wk; dst = Wb + M1;     n = M1; break;
    default: src = Wv; dst = Wb + 2*M1;  n = M1; break;
  }
  int i = (blockIdx.x * 256 + threadIdx.x) * 4;
  const int stride = gridDim.x * 256 * 4;
  for (; i < n; i += stride) {
    const float4 v = *(const float4*)(src + i);
    f16x4 o;
    o.x = (_Float16)v.x; o.y = (_Float16)v.y; o.z = (_Float16)v.z; o.w = (_Float16)v.w;
    *(f16x4*)(dst + i) = o;
  }
}

// 256x256 tiles over [M=8192, Ncat=3072]; z = ncat>>10 selects Q/K/V.
__global__ __launch_bounds__(512, 2) void qkv_gemm(
    const _Float16* __restrict__ xb, const _Float16* __restrict__ Wb,
    const float* __restrict__ bq, const float* __restrict__ bk,
    const float* __restrict__ bv,
    _Float16* __restrict__ Qb, _Float16* __restrict__ Kb, _Float16* __restrict__ Vt)
{
  __shared__ _Float16 As[24576];   // 3 x 256 x 32
  __shared__ _Float16 Bs[24576];
  const int m0 = blockIdx.x * 256;
  const int ng = blockIdx.y * 256;
  const int z  = ng >> 10;
  const int n0 = ng & 1023;

  f32x4 acc[8][4];
#pragma unroll
  for (int mi = 0; mi < 8; ++mi)
#pragma unroll
    for (int ni = 0; ni < 4; ++ni) acc[mi][ni] = {0.f, 0.f, 0.f, 0.f};

  gemm256<32>(xb + (size_t)m0 * DIM, DIM,
              Wb + (size_t)z * DIM * DIM + (size_t)n0 * DIM, DIM,
              As, Bs, acc);

  const int t = threadIdx.x, wv = t >> 6, ln = t & 63, lr = ln & 15, lq = ln >> 4;
  const int wm = wv & 1, wn = wv >> 1;
  const float* bias = (z == 0) ? bq : (z == 1) ? bk : bv;
  if (z < 2) {
    _Float16* O = (z == 0) ? Qb : Kb;
#pragma unroll
    for (int ni = 0; ni < 4; ++ni) {
      const int col = n0 + wn * 64 + ni * 16 + lr;
      const float bb = bias[col];
#pragma unroll
      for (int mi = 0; mi < 8; ++mi) {
        const int r0 = m0 + wm * 128 + mi * 16 + lq * 4;
#pragma unroll
        for (int r = 0; r < 4; ++r)
          O[(size_t)(r0 + r) * DIM + col] = (_Float16)(acc[mi][ni][r] + bb);
      }
    }
  } else {
#pragma unroll
    for (int ni = 0; ni < 4; ++ni) {
      const int col = n0 + wn * 64 + ni * 16 + lr;
      const float bb = bias[col];
#pragma unroll
      for (int mi = 0; mi < 8; ++mi) {
        const int r0 = m0 + wm * 128 + mi * 16 + lq * 4;
        const int b = r0 >> 11, s = r0 & 2047;
        f16x4 pk;
#pragma unroll
        for (int r = 0; r < 4; ++r) pk[r] = (_Float16)(acc[mi][ni][r] + bb);
        *(f16x4*)(Vt + (size_t)b * DIM * SEQ + (size_t)col * SEQ + s) = pk;
      }
    }
  }
}

// Fused QK^T + exp + row-sum on 256x256 tri tiles (qt,kt in 0..7, kt<=qt).
// Writes the packed-tri 128-row P layout pv consumes: per wave qt128=2qt+wm.
__global__ __launch_bounds__(512, 2) void qk_gemm(
    const _Float16* __restrict__ Qb, const _Float16* __restrict__ Kb,
    _Float16* __restrict__ Pm, float* __restrict__ lsum)
{
  __shared__ _Float16 As[24576];   // 3 x 256 x 32
  __shared__ _Float16 Bs[24576];
  const int idx = blockIdx.x;
  int qt = 0;
  while ((qt + 1) * (qt + 2) / 2 <= idx) ++qt;
  const int kt = idx - qt * (qt + 1) / 2;
  const int q0 = qt * 256, k0 = kt * 256, b = blockIdx.y;

  f32x4 acc[8][4];
#pragma unroll
  for (int mi = 0; mi < 8; ++mi)
#pragma unroll
    for (int ni = 0; ni < 4; ++ni) acc[mi][ni] = {0.f, 0.f, 0.f, 0.f};

  const _Float16* Qp = Qb + (size_t)b * SEQ * DIM + (size_t)q0 * DIM;
  const _Float16* Kp = Kb + (size_t)b * SEQ * DIM + (size_t)k0 * DIM;
  gemm256<32>(Qp, DIM, Kp, DIM, As, Bs, acc);

  const int t = threadIdx.x, wv = t >> 6, ln = t & 63, lr = ln & 15, lq = ln >> 4;
  const int wm = wv & 1, wn = wv >> 1;
  const int qt128 = 2 * qt + wm;                   // uniform per wave
  const int ldp = (qt128 + 1) * 128;
  _Float16* scr = Pm + (size_t)b * PBATCH + (size_t)(qt128 * (qt128 + 1) / 2) * 16384;
  float* lrow = lsum + b * SEQ;

  float es[8][4];
#pragma unroll
  for (int mi = 0; mi < 8; ++mi)
#pragma unroll
    for (int r = 0; r < 4; ++r) es[mi][r] = 0.f;

#pragma unroll
  for (int ni = 0; ni < 4; ++ni) {
    const int col = k0 + wn * 64 + ni * 16 + lr;
    const bool cin = col < ldp;
#pragma unroll
    for (int mi = 0; mi < 8; ++mi) {
#pragma unroll
      for (int r = 0; r < 4; ++r) {
        const int rin = mi * 16 + lq * 4 + r;      // 0..127 within row group
        const int row = q0 + wm * 128 + rin;
        const float s = acc[mi][ni][r] * SCL;
        const float e = (col <= row) ? __expf(fminf(s, 10.f)) : 0.f;
        if (cin) scr[(size_t)rin * ldp + col] = (_Float16)e;
        es[mi][r] += e;
      }
    }
  }
#pragma unroll
  for (int mi = 0; mi < 8; ++mi)
#pragma unroll
    for (int r = 0; r < 4; ++r) {
      float v = es[mi][r];
#pragma unroll
      for (int off = 1; off < 16; off <<= 1) v += __shfl_xor(v, off, 64);
      if (lr == 0) {
        const int row = q0 + wm * 128 + mi * 16 + lq * 4 + r;
        atomicAdd(&lrow[row], v);
      }
    }
}

// out[b][q][d] = (sum_k e[q][k] * Vt[b][d][k]) / l[b][q].
// q split into 32 subtiles of 64 rows, paired j & 31-j -> 17 K-tiles/block.
__global__ __launch_bounds__(256, 2) void pv_gemm(
    const _Float16* __restrict__ Pm, const _Float16* __restrict__ Vt,
    const float* __restrict__ lsum, float* __restrict__ out)
{
  __shared__ _Float16 As[8192];     // 2 x 64 x 64
  __shared__ _Float16 Bs[16384];    // 2 x 128 x 64
  const int p  = blockIdx.x;        // 0..15
  const int d0 = blockIdx.y * 128;
  const int b  = blockIdx.z;

  const int t = threadIdx.x, wv = t >> 6, ln = t & 63, lr = ln & 15, lq = ln >> 4;
  const int wm = wv & 1, wn = wv >> 1;
  float* O = out + (size_t)b * SEQ * DIM;
  const float* lrow = lsum + b * SEQ;
  const _Float16* Vp = Vt + (size_t)b * DIM * SEQ + (size_t)d0 * SEQ;

  const int js[2] = { 31 - p, p };  // big subtile first
#pragma unroll
  for (int u = 0; u < 2; ++u) {
    const int j  = js[u];
    const int qt = j >> 1;
    const int q0 = qt * 128 + (j & 1) * 64;
    const int K  = (qt + 1) * 128;
    if (u) __syncthreads();

    f32x4 acc[2][4];
#pragma unroll
    for (int mi = 0; mi < 2; ++mi)
#pragma unroll
      for (int ni = 0; ni < 4; ++ni) acc[mi][ni] = {0.f, 0.f, 0.f, 0.f};

    const _Float16* Pp = Pm + (size_t)b * PBATCH
        + (size_t)(qt * (qt + 1) / 2) * 16384 + (size_t)(j & 1) * 64 * K;
    gemm_core64_db<64,128>(Pp, K, Vp, SEQ, K, As, Bs, acc);

#pragma unroll
    for (int mi = 0; mi < 2; ++mi) {
      const int r0 = q0 + wm * 32 + mi * 16 + lq * 4;
      const float4 lv = *(const float4*)(lrow + r0);
      const float inv[4] = {1.f / lv.x, 1.f / lv.y, 1.f / lv.z, 1.f / lv.w};
#pragma unroll
      for (int ni = 0; ni < 4; ++ni) {
        const int col = d0 + wn * 64 + ni * 16 + lr;
#pragma unroll
        for (int r = 0; r < 4; ++r)
          O[(size_t)(r0 + r) * DIM + col] = acc[mi][ni][r] * inv[r];
      }
    }
  }
}

extern "C" void kernel_launch(void* const* d_in, const int* in_sizes, int n_in,
                              void* d_out, int out_size, void* d_ws, size_t ws_size,
                              hipStream_t stream) {
  const float* x  = (const float*)d_in[0];
  const float* Wq = (const float*)d_in[1];
  const float* bq = (const float*)d_in[2];
  const float* Wk = (const float*)d_in[3];
  const float* bk = (const float*)d_in[4];
  const float* Wv = (const float*)d_in[5];
  const float* bv = (const float*)d_in[6];
  float* out = (float*)d_out;

  _Float16* w16 = (_Float16*)d_ws;
  const size_t M1 = (size_t)1024 * 1024;
  _Float16* Qb = w16;                 //  0M .. 8M el (16 MB)
  _Float16* Kb = w16 + 8 * M1;        //  8M .. 16M
  _Float16* Vt = w16 + 16 * M1;       // 16M .. 24M  (V transposed [b][d][s])
  _Float16* xb = w16 + 24 * M1;       // 24M .. 32M  (dead after qkv_gemm)
  _Float16* Wb = w16 + 32 * M1;       // 32M .. 35M  (dead after qkv_gemm)
  _Float16* Pm = w16 + 24 * M1;       // packed tri P (17.8 MB), aliases xb
  float*    lsum = (float*)(w16 + 34 * M1);  // 32 KB row sums

  hipMemsetAsync(lsum, 0, NB * SEQ * sizeof(float), stream);
  cvt_all<<<dim3(512, 4), 256, 0, stream>>>(x, Wq, Wk, Wv, xb, Wb);
  qkv_gemm<<<dim3(32, 12), 512, 0, stream>>>(xb, Wb, bq, bk, bv, Qb, Kb, Vt);
  qk_gemm<<<dim3(36, NB), 512, 0, stream>>>(Qb, Kb, Pm, lsum);
  pv_gemm<<<dim3(16, 8, NB), 256, 0, stream>>>(Pm, Vt, lsum, out);
}

// Round 6
// 253.274 us; speedup vs baseline: 1.0544x; 1.0196x over previous
//
#include <hip/hip_runtime.h>

// CausalAttention: B=4, S=2048, D=1024, single head over full D.
// R10: revert qkv+qk to the R5 2-phase BK=64 double-buffered 128x128 core
// (measured best: qkv 68us). pv keeps R6's perfectly-balanced pairing
// (j & 31-j, 17 K-tiles/block) but its core gains DEPTH-2 prefetch via a
// third LDS buffer (72 KB, still 2 blocks/CU): stage tile t+2 while
// computing tile t, boundary vmcnt(6) waits only for t+1 (t+2 in flight)
// -> ~2 K-steps (~700cyc) of latency cover for pv's L3-resident P/Vt
// operands, vs depth-1's single step. Only pv changes vs the R5/R6 pieces.

typedef __attribute__((ext_vector_type(8))) _Float16 f16x8;
typedef __attribute__((ext_vector_type(4))) _Float16 f16x4;
typedef __attribute__((ext_vector_type(4))) float f32x4;

#define NB   4
#define SEQ  2048
#define DIM  1024
#define SCL  0.03125f   // 1/sqrt(1024)
#define PBATCH (136 * 16384)   // packed P elems per batch (tri(16) tiles)

__device__ __forceinline__ void gll16(const _Float16* g, _Float16* l) {
  __builtin_amdgcn_global_load_lds(
      (__attribute__((address_space(1))) void*)(g),
      (__attribute__((address_space(3))) void*)(l), 16, 0, 0);
}

// ---------------- BK=64 double-buffered 2-phase core (qkv, qk) ----------------
// As/Bs [2][128][64] fp16 (32 KB each). Row = 128 B = all 32 banks, so
// swizzle chunk' = chunk ^ (row&7) over the 8 16B-chunks/row -> 2-way (free).
// Pipeline per K-tile: stage(next half) -> s_waitcnt vmcnt(8) (prev tile
// landed, next stays in flight) -> s_barrier -> ds_read + MFMA -> s_barrier.
__device__ __forceinline__ void gemm_core64_db(
    const _Float16* __restrict__ A, int lda,
    const _Float16* __restrict__ Bm, int ldb,
    int K, _Float16* As, _Float16* Bs, f32x4 acc[4][4])
{
  const int t    = threadIdx.x;
  const int wv   = t >> 6;
  const int ln   = t & 63;
  const int lr   = ln & 15;
  const int lq   = ln >> 4;
  const int rsub = ln >> 3;                       // 0..7
  const int colb = (((ln & 7) ^ rsub) * 8);       // swizzled source chunk

  const _Float16* ga[4]; const _Float16* gb[4];
  _Float16* dA[4]; _Float16* dB[4];
#pragma unroll
  for (int l = 0; l < 4; ++l) {
    const int row = (4 * l + wv) * 8 + rsub;
    ga[l] = A  + row * lda + colb;
    gb[l] = Bm + row * ldb + colb;
    dA[l] = As + (4 * l + wv) * 512;              // 512 elems = 1 KB per line
    dB[l] = Bs + (4 * l + wv) * 512;
  }

  const int swzr = lr & 7;
  const int ra = (((wv & 1) * 64) + lr) * 64;
  const int rb = (((wv >> 1) * 64) + lr) * 64;
  const int c0 = ((0 * 4 + lq) ^ swzr) * 8;
  const int c1 = ((1 * 4 + lq) ^ swzr) * 8;

  auto compute = [&](int half) {
    const _Float16* pa = As + half * 8192 + ra;
    const _Float16* pb = Bs + half * 8192 + rb;
    f16x8 af[4][2], bf[4][2];
#pragma unroll
    for (int mi = 0; mi < 4; ++mi) {
      af[mi][0] = *(const f16x8*)(pa + mi * 1024 + c0);
      af[mi][1] = *(const f16x8*)(pa + mi * 1024 + c1);
    }
#pragma unroll
    for (int ni = 0; ni < 4; ++ni) {
      bf[ni][0] = *(const f16x8*)(pb + ni * 1024 + c0);
      bf[ni][1] = *(const f16x8*)(pb + ni * 1024 + c1);
    }
#pragma unroll
    for (int ks = 0; ks < 2; ++ks)
#pragma unroll
      for (int mi = 0; mi < 4; ++mi)
#pragma unroll
        for (int ni = 0; ni < 4; ++ni)
          acc[mi][ni] = __builtin_amdgcn_mfma_f32_16x16x32_f16(
              af[mi][ks], bf[ni][ks], acc[mi][ni], 0, 0, 0);
  };

  // prologue: stage tile 0 into half 0
#pragma unroll
  for (int l = 0; l < 4; ++l) gll16(ga[l], dA[l]);
#pragma unroll
  for (int l = 0; l < 4; ++l) gll16(gb[l], dB[l]);

  int cur = 0;
  for (int k0 = 64; k0 < K; k0 += 64) {
    const int nxt = cur ^ 1;
#pragma unroll
    for (int l = 0; l < 4; ++l) gll16(ga[l] + k0, dA[l] + nxt * 8192);
#pragma unroll
    for (int l = 0; l < 4; ++l) gll16(gb[l] + k0, dB[l] + nxt * 8192);
    asm volatile("s_waitcnt vmcnt(8)" ::: "memory");  // prev tile landed
    __builtin_amdgcn_s_barrier();
    compute(cur);
    __builtin_amdgcn_s_barrier();   // lgkm already drained by MFMA consumption
    cur = nxt;
  }
  asm volatile("s_waitcnt vmcnt(0)" ::: "memory");
  __builtin_amdgcn_s_barrier();
  compute(cur);
}

// ---------------- pv core: 64x128, BK=64, TRIPLE-buffered (depth-2) -------
// As: 3 x [64][64] (24 KB), Bs: 3 x [128][64] (48 KB). Same swizzle/frag
// layout as the 2-phase core; only prefetch depth differs: stage tile t+2
// while computing t; boundary waits vmcnt(6) (tile t+1 landed, t+2's 6
// loads in flight). Never drains to 0 except at the last tile.
__device__ __forceinline__ void gemm_pv3(
    const _Float16* __restrict__ A, int lda,
    const _Float16* __restrict__ Bm, int ldb,
    int K, _Float16* As, _Float16* Bs, f32x4 acc[2][4])
{
  const int t    = threadIdx.x;
  const int wv   = t >> 6;
  const int ln   = t & 63;
  const int lr   = ln & 15;
  const int lq   = ln >> 4;
  const int rsub = ln >> 3;
  const int colb = (((ln & 7) ^ rsub) * 8);

  const _Float16* ga[2]; int dA[2];
  const _Float16* gb[4]; int dB[4];
#pragma unroll
  for (int l = 0; l < 2; ++l) {
    const int row = (4 * l + wv) * 8 + rsub;
    ga[l] = A + row * lda + colb;
    dA[l] = (4 * l + wv) * 512;
  }
#pragma unroll
  for (int l = 0; l < 4; ++l) {
    const int row = (4 * l + wv) * 8 + rsub;
    gb[l] = Bm + row * ldb + colb;
    dB[l] = (4 * l + wv) * 512;
  }

  const int swzr = lr & 7;
  const int ra = (((wv & 1) * 32) + lr) * 64;     // AR/2 = 32
  const int rb = (((wv >> 1) * 64) + lr) * 64;
  const int c0 = ((lq) ^ swzr) * 8;
  const int c1 = ((4 + lq) ^ swzr) * 8;

  auto stage = [&](int k0, int ab, int bb) {
#pragma unroll
    for (int l = 0; l < 2; ++l) gll16(ga[l] + k0, As + ab + dA[l]);
#pragma unroll
    for (int l = 0; l < 4; ++l) gll16(gb[l] + k0, Bs + bb + dB[l]);
  };
  auto compute = [&](int ab, int bb) {
    const _Float16* pa = As + ab + ra;
    const _Float16* pb = Bs + bb + rb;
    f16x8 af[2][2], bf[4][2];
#pragma unroll
    for (int mi = 0; mi < 2; ++mi) {
      af[mi][0] = *(const f16x8*)(pa + mi * 1024 + c0);
      af[mi][1] = *(const f16x8*)(pa + mi * 1024 + c1);
    }
#pragma unroll
    for (int ni = 0; ni < 4; ++ni) {
      bf[ni][0] = *(const f16x8*)(pb + ni * 1024 + c0);
      bf[ni][1] = *(const f16x8*)(pb + ni * 1024 + c1);
    }
#pragma unroll
    for (int ks = 0; ks < 2; ++ks)
#pragma unroll
      for (int mi = 0; mi < 2; ++mi)
#pragma unroll
        for (int ni = 0; ni < 4; ++ni)
          acc[mi][ni] = __builtin_amdgcn_mfma_f32_16x16x32_f16(
              af[mi][ks], bf[ni][ks], acc[mi][ni], 0, 0, 0);
  };

  const int NT = K >> 6;                 // >= 2 always (K >= 128)
  // buffer elem offsets (A: 4096/buf, B: 8192/buf)
  int a0 = 0, a1 = 4096, a2 = 8192;
  int b0 = 0, b1 = 8192, b2 = 16384;

  // prologue: stage tiles 0 and 1
  stage(0, a0, b0);
  stage(64, a1, b1);
  asm volatile("s_waitcnt vmcnt(6)" ::: "memory");   // tile 0 landed
  __builtin_amdgcn_s_barrier();

  for (int tt = 0; tt < NT; ++tt) {
    if (tt + 2 < NT) stage((tt + 2) * 64, a2, b2);
    compute(a0, b0);
    if (tt + 1 < NT) {
      if (tt + 2 < NT)
        asm volatile("s_waitcnt vmcnt(6)" ::: "memory");  // t+1 landed
      else
        asm volatile("s_waitcnt vmcnt(0)" ::: "memory");  // last tile
      __builtin_amdgcn_s_barrier();
    }
    const int ta = a0; a0 = a1; a1 = a2; a2 = ta;
    const int tb = b0; b0 = b1; b1 = b2; b2 = tb;
  }
}

// one kernel converts x, Wq, Wk, Wv (blockIdx.y selects segment)
__global__ __launch_bounds__(256) void cvt_all(
    const float* __restrict__ x, const float* __restrict__ Wq,
    const float* __restrict__ Wk, const float* __restrict__ Wv,
    _Float16* __restrict__ xb, _Float16* __restrict__ Wb)
{
  const float* src; _Float16* dst; int n;
  const int M1 = 1024 * 1024;
  switch (blockIdx.y) {
    case 0: src = x;  dst = xb;          n = NB * SEQ * DIM; break;
    case 1: src = Wq; dst = Wb;          n = M1; break;
    case 2: src = Wk; dst = Wb + M1;     n = M1; break;
    default: src = Wv; dst = Wb + 2*M1;  n = M1; break;
  }
  int i = (blockIdx.x * 256 + threadIdx.x) * 4;
  const int stride = gridDim.x * 256 * 4;
  for (; i < n; i += stride) {
    const float4 v = *(const float4*)(src + i);
    f16x4 o;
    o.x = (_Float16)v.x; o.y = (_Float16)v.y; o.z = (_Float16)v.z; o.w = (_Float16)v.w;
    *(f16x4*)(dst + i) = o;
  }
}

// z=0: Q -> Qb; z=1: K -> Kb; z=2: V -> Vt [b][d][s] (transposed)
__global__ __launch_bounds__(256, 2) void qkv_gemm(
    const _Float16* __restrict__ xb, const _Float16* __restrict__ Wb,
    const float* __restrict__ bq, const float* __restrict__ bk,
    const float* __restrict__ bv,
    _Float16* __restrict__ Qb, _Float16* __restrict__ Kb, _Float16* __restrict__ Vt)
{
  __shared__ _Float16 As[16384];
  __shared__ _Float16 Bs[16384];
  const int m0 = blockIdx.x * 128;
  const int n0 = blockIdx.y * 128;
  const int z  = blockIdx.z;
  f32x4 acc[4][4];
#pragma unroll
  for (int mi = 0; mi < 4; ++mi)
#pragma unroll
    for (int ni = 0; ni < 4; ++ni) acc[mi][ni] = {0.f, 0.f, 0.f, 0.f};

  gemm_core64_db(xb + (size_t)m0 * DIM, DIM,
                 Wb + (size_t)z * DIM * DIM + (size_t)n0 * DIM, DIM,
                 DIM, As, Bs, acc);

  const int t = threadIdx.x, wv = t >> 6, ln = t & 63, lr = ln & 15, lq = ln >> 4;
  const int wm = wv & 1, wn = wv >> 1;
  const float* bias = (z == 0) ? bq : (z == 1) ? bk : bv;
  if (z < 2) {
    _Float16* O = (z == 0) ? Qb : Kb;
#pragma unroll
    for (int ni = 0; ni < 4; ++ni) {
      const int col = n0 + wn * 64 + ni * 16 + lr;
      const float bb = bias[col];
#pragma unroll
      for (int mi = 0; mi < 4; ++mi) {
        const int r0 = m0 + wm * 64 + mi * 16 + lq * 4;
#pragma unroll
        for (int r = 0; r < 4; ++r)
          O[(size_t)(r0 + r) * DIM + col] = (_Float16)(acc[mi][ni][r] + bb);
      }
    }
  } else {
#pragma unroll
    for (int ni = 0; ni < 4; ++ni) {
      const int col = n0 + wn * 64 + ni * 16 + lr;
      const float bb = bias[col];
#pragma unroll
      for (int mi = 0; mi < 4; ++mi) {
        const int r0 = m0 + wm * 64 + mi * 16 + lq * 4;
        const int b = r0 >> 11, s = r0 & 2047;
        f16x4 pk;
#pragma unroll
        for (int r = 0; r < 4; ++r) pk[r] = (_Float16)(acc[mi][ni][r] + bb);
        *(f16x4*)(Vt + (size_t)b * DIM * SEQ + (size_t)col * SEQ + s) = pk;
      }
    }
  }
}

// Fused QK^T + exp + row-sum. Grid x = 136 lower-tri tiles, y = batch.
__global__ __launch_bounds__(256, 2) void qk_gemm(
    const _Float16* __restrict__ Qb, const _Float16* __restrict__ Kb,
    _Float16* __restrict__ Pm, float* __restrict__ lsum)
{
  const int idx = blockIdx.x;
  int qt = 0;
  while ((qt + 1) * (qt + 2) / 2 <= idx) ++qt;
  const int kt = idx - qt * (qt + 1) / 2;
  const int q0 = qt * 128, k0 = kt * 128, b = blockIdx.y;

  __shared__ _Float16 As[16384];
  __shared__ _Float16 Bs[16384];
  f32x4 acc[4][4];
#pragma unroll
  for (int mi = 0; mi < 4; ++mi)
#pragma unroll
    for (int ni = 0; ni < 4; ++ni) acc[mi][ni] = {0.f, 0.f, 0.f, 0.f};

  const _Float16* Qp = Qb + (size_t)b * SEQ * DIM + (size_t)q0 * DIM;
  const _Float16* Kp = Kb + (size_t)b * SEQ * DIM + (size_t)k0 * DIM;
  gemm_core64_db(Qp, DIM, Kp, DIM, DIM, As, Bs, acc);

  const int t = threadIdx.x, wv = t >> 6, ln = t & 63, lr = ln & 15, lq = ln >> 4;
  const int wm = wv & 1, wn = wv >> 1;
  const int ldp = (qt + 1) * 128;
  _Float16* scr = Pm + (size_t)b * PBATCH + (size_t)(qt * (qt + 1) / 2) * 16384;
  float* lrow = lsum + b * SEQ;

  float es[4][4];
#pragma unroll
  for (int mi = 0; mi < 4; ++mi)
#pragma unroll
    for (int r = 0; r < 4; ++r) es[mi][r] = 0.f;

#pragma unroll
  for (int ni = 0; ni < 4; ++ni) {
    const int col = k0 + wn * 64 + ni * 16 + lr;
#pragma unroll
    for (int mi = 0; mi < 4; ++mi) {
      const int r0 = q0 + wm * 64 + mi * 16 + lq * 4;
#pragma unroll
      for (int r = 0; r < 4; ++r) {
        const int row = r0 + r;
        const float s = acc[mi][ni][r] * SCL;
        const float e = (col <= row) ? __expf(fminf(s, 10.f)) : 0.f;
        scr[(size_t)(row - q0) * ldp + col] = (_Float16)e;
        es[mi][r] += e;
      }
    }
  }
#pragma unroll
  for (int mi = 0; mi < 4; ++mi)
#pragma unroll
    for (int r = 0; r < 4; ++r) {
      float v = es[mi][r];
#pragma unroll
      for (int off = 1; off < 16; off <<= 1) v += __shfl_xor(v, off, 64);
      if (lr == 0) {
        const int row = q0 + wm * 64 + mi * 16 + lq * 4 + r;
        atomicAdd(&lrow[row], v);
      }
    }
}

// out[b][q][d] = (sum_k e[q][k] * Vt[b][d][k]) / l[b][q].
// q split into 32 subtiles of 64 rows, paired j & 31-j -> 17 K-tiles/block.
// Core is depth-2 triple-buffered (see gemm_pv3).
__global__ __launch_bounds__(256, 2) void pv_gemm(
    const _Float16* __restrict__ Pm, const _Float16* __restrict__ Vt,
    const float* __restrict__ lsum, float* __restrict__ out)
{
  __shared__ _Float16 As[12288];    // 3 x 64 x 64
  __shared__ _Float16 Bs[24576];    // 3 x 128 x 64
  const int p  = blockIdx.x;        // 0..15
  const int d0 = blockIdx.y * 128;
  const int b  = blockIdx.z;

  const int t = threadIdx.x, wv = t >> 6, ln = t & 63, lr = ln & 15, lq = ln >> 4;
  const int wm = wv & 1, wn = wv >> 1;
  float* O = out + (size_t)b * SEQ * DIM;
  const float* lrow = lsum + b * SEQ;
  const _Float16* Vp = Vt + (size_t)b * DIM * SEQ + (size_t)d0 * SEQ;

  const int js[2] = { 31 - p, p };  // big subtile first
#pragma unroll
  for (int u = 0; u < 2; ++u) {
    const int j  = js[u];
    const int qt = j >> 1;
    const int q0 = qt * 128 + (j & 1) * 64;
    const int K  = (qt + 1) * 128;  // upper-tri cols hold stored zeros
    if (u) __syncthreads();         // LDS reuse hazard between the pair

    f32x4 acc[2][4];
#pragma unroll
    for (int mi = 0; mi < 2; ++mi)
#pragma unroll
      for (int ni = 0; ni < 4; ++ni) acc[mi][ni] = {0.f, 0.f, 0.f, 0.f};

    const _Float16* Pp = Pm + (size_t)b * PBATCH
        + (size_t)(qt * (qt + 1) / 2) * 16384 + (size_t)(j & 1) * 64 * K;
    gemm_pv3(Pp, K, Vp, SEQ, K, As, Bs, acc);

#pragma unroll
    for (int mi = 0; mi < 2; ++mi) {
      const int r0 = q0 + wm * 32 + mi * 16 + lq * 4;
      const float4 lv = *(const float4*)(lrow + r0);
      const float inv[4] = {1.f / lv.x, 1.f / lv.y, 1.f / lv.z, 1.f / lv.w};
#pragma unroll
      for (int ni = 0; ni < 4; ++ni) {
        const int col = d0 + wn * 64 + ni * 16 + lr;
#pragma unroll
        for (int r = 0; r < 4; ++r)
          O[(size_t)(r0 + r) * DIM + col] = acc[mi][ni][r] * inv[r];
      }
    }
  }
}

extern "C" void kernel_launch(void* const* d_in, const int* in_sizes, int n_in,
                              void* d_out, int out_size, void* d_ws, size_t ws_size,
                              hipStream_t stream) {
  const float* x  = (const float*)d_in[0];
  const float* Wq = (const float*)d_in[1];
  const float* bq = (const float*)d_in[2];
  const float* Wk = (const float*)d_in[3];
  const float* bk = (const float*)d_in[4];
  const float* Wv = (const float*)d_in[5];
  const float* bv = (const float*)d_in[6];
  float* out = (float*)d_out;

  _Float16* w16 = (_Float16*)d_ws;
  const size_t M1 = (size_t)1024 * 1024;
  _Float16* Qb = w16;                 //  0M .. 8M el (16 MB)
  _Float16* Kb = w16 + 8 * M1;        //  8M .. 16M
  _Float16* Vt = w16 + 16 * M1;       // 16M .. 24M  (V transposed [b][d][s])
  _Float16* xb = w16 + 24 * M1;       // 24M .. 32M  (dead after qkv_gemm)
  _Float16* Wb = w16 + 32 * M1;       // 32M .. 35M  (dead after qkv_gemm)
  _Float16* Pm = w16 + 24 * M1;       // packed tri P (17.8 MB), aliases xb
  float*    lsum = (float*)(w16 + 34 * M1);  // 32 KB row sums

  hipMemsetAsync(lsum, 0, NB * SEQ * sizeof(float), stream);
  cvt_all<<<dim3(512, 4), 256, 0, stream>>>(x, Wq, Wk, Wv, xb, Wb);
  qkv_gemm<<<dim3(64, 8, 3), 256, 0, stream>>>(xb, Wb, bq, bk, bv, Qb, Kb, Vt);
  qk_gemm<<<dim3(136, NB), 256, 0, stream>>>(Qb, Kb, Pm, lsum);
  pv_gemm<<<dim3(16, 8, NB), 256, 0, stream>>>(Pm, Vt, lsum, out);
}